// Round 4
// baseline (83.922 us; speedup 1.0000x reference)
//
#include <hip/hip_runtime.h>

// Problem constants (from reference)
#define KK 2
#define BB 4
#define VV 2000
#define DD 64
#define HH 4
#define DHH 64
#define PP 128
#define ALPHA_ 0.2f

// k_attn geometry
#define RPW 8                 // rows per wave
#define NWV 4                 // waves per block
#define RPB (RPW * NWV)       // 32 rows per block-tile
#define YB  8                 // y-blocks (tiles strided by YB)
#define KT  128               // source rows per LDS chunk
#define NBLK (KK * BB * YB * HH)  // 256 total k_attn blocks

__device__ __forceinline__ float lrelu(float z) { return z >= 0.f ? z : ALPHA_ * z; }
__device__ __forceinline__ float elu_(float z)  { return z > 0.f ? z : expm1f(z); }
__device__ __forceinline__ float rdlane(float v, int sl) {
  return __uint_as_float(__builtin_amdgcn_readlane(__float_as_uint(v), (unsigned)sl));
}

// ---------------------------------------------------------------------------
// Workspace layout (float offsets):
//   EW  [H][V][DH]   : 0        (512000)
//   F1  [H][V]       : 512000   (8000)
//   F2  [H][V]       : 520000   (8000)
//   LAT [K][B][256]  : 528000   (2048)
//   CNT (int)[8]     : 530048   (8)
//   S   (int)[K*B][V]: 530056   (16000)
//   DONE (int)       : 546056   (1)
// ---------------------------------------------------------------------------
#define OFF_EW   0
#define OFF_F1   512000
#define OFF_F2   520000
#define OFF_LAT  528000
#define OFF_CNT  530048
#define OFF_S    530056
#define OFF_DONE 546056

// ---- kernel 0 (fused): EW/F1/F2 precompute (present rows only) + compaction
// blocks [0, 2000): EW — h = bid/500 (h-major keeps W_h L1-hot), 4 v per block
// blocks [2000, 2008): compaction for kb = bid-2000 (wave 0 only)
__global__ __launch_bounds__(256) void k_pre(
    const float* __restrict__ E, const float* __restrict__ W,
    const float* __restrict__ a1, const float* __restrict__ a2,
    const float* __restrict__ x,
    float* __restrict__ EW, float* __restrict__ F1, float* __restrict__ F2,
    int* __restrict__ S, int* __restrict__ cnt, float* __restrict__ lat,
    int* __restrict__ done) {
  const int bid = blockIdx.x;
  const int wave = threadIdx.x >> 6, lane = threadIdx.x & 63;
  if (bid < 2000) {
    const int h = bid / 500;
    const int v = (bid % 500) * 4 + wave;
    // skip rows absent in every (k,b) slice: their EW/F1/F2 are never read
    bool pres = false;
#pragma unroll
    for (int kb = 0; kb < KK * BB; ++kb) pres |= (x[kb * VV + v] > 0.f);
    if (!pres) return;
    const float* Wh = W + h * DD * DHH;
    const float* Ev = E + v * DD;
    float acc = 0.f;
#pragma unroll 8
    for (int d = 0; d < DD; ++d) acc = fmaf(Ev[d], Wh[d * DHH + lane], acc);
    EW[(h * VV + v) * DHH + lane] = acc;
    float r1 = acc * a1[h * DHH + lane];
    float r2 = acc * a2[h * DHH + lane];
#pragma unroll
    for (int s = 32; s; s >>= 1) { r1 += __shfl_xor(r1, s); r2 += __shfl_xor(r2, s); }
    if (lane == 0) { F1[h * VV + v] = r1; F2[h * VV + v] = r2; }
  } else {
    if (wave != 0) return;
    const int kb = bid - 2000;  // 0..7
    if (kb == 0 && lane == 0) *done = 0;   // reset arrival counter each call
    for (int i = lane; i < 256; i += 64) lat[kb * 256 + i] = 0.f;
    const float* xr = x + kb * VV;
    int base = 0;
    for (int t = 0; t * 64 < VV; ++t) {
      const int v = t * 64 + lane;
      const bool f = (v < VV) && (xr[v] > 0.f);
      const unsigned long long m = __ballot(f);
      if (f) {
        const int pos = base + __popcll(m & ((1ull << lane) - 1ull));
        S[kb * VV + pos] = v;
      }
      base += __popcll(m);
    }
    if (lane == 0) cnt[kb] = base;
  }
}

// ---- kernel 1: attention rows + fused finale ------------------------------
// block = (kb, y, h); tiles of 32 rows strided by YB; 4 waves x 8 rows.
// Hot loop: EWg from LDS (1 ds_read_b32), probs from VGPRs via v_readlane.
// Last-arriving block (device-scope counter) runs the pooling+dense head.
__global__ __launch_bounds__(256) void k_attn(
    const float* __restrict__ EW, const float* __restrict__ F1,
    const float* __restrict__ F2, const int* __restrict__ S,
    const int* __restrict__ cnt, float* __restrict__ lat,
    const float* __restrict__ cls_w, const float* __restrict__ ac1,
    const float* __restrict__ ac2, const float* __restrict__ dW,
    const float* __restrict__ db, float* __restrict__ out,
    int* __restrict__ done) {
  __shared__ float EWg[KT][DHH];   // 32 KB gathered EW chunk
  __shared__ float G2l[2048];      // 8 KB gathered F2 (full present set)
  __shared__ int s_last;
  __shared__ float pooled[256];
  __shared__ float red[4][4];

  const int kb = blockIdx.x;       // 0..7
  const int h = blockIdx.z;        // 0..3
  const int tid = threadIdx.x;
  const int wave = tid >> 6, lane = tid & 63;
  const int n = cnt[kb];
  const int nt = (n + RPB - 1) / RPB;

  if ((int)blockIdx.y < nt) {
    const int* Skb = S + kb * VV;
    const float* F2h = F2 + h * VV;
    const float* F1h = F1 + h * VV;
    const float* EWh = EW + (size_t)h * VV * DHH;
    int* latp = reinterpret_cast<int*>(&lat[kb * 256 + h * DHH + lane]);

    // stage gathered F2 once per block (read-only afterwards)
    for (int j = tid; j < n; j += 256) G2l[j] = F2h[Skb[j]];
    __syncthreads();

    for (int tile = blockIdx.y; tile < nt; tile += YB) {
      const int r0 = tile * RPB + wave * RPW;
      bool act[RPW]; float f1r[RPW];
#pragma unroll
      for (int i = 0; i < RPW; ++i) {
        const int r = r0 + i;
        act[i] = r < n;
        f1r[i] = F1h[Skb[act[i] ? r : 0]];
      }
      // pass A: per-row max
      float m[RPW];
#pragma unroll
      for (int i = 0; i < RPW; ++i) m[i] = -3.4e38f;
      for (int jb = lane; jb < n; jb += 64) {
        const float g = G2l[jb];
#pragma unroll
        for (int i = 0; i < RPW; ++i) m[i] = fmaxf(m[i], lrelu(f1r[i] + g));
      }
#pragma unroll
      for (int s = 32; s; s >>= 1)
#pragma unroll
        for (int i = 0; i < RPW; ++i) m[i] = fmaxf(m[i], __shfl_xor(m[i], s));
      // pass B: per-row sum
      float sm[RPW];
#pragma unroll
      for (int i = 0; i < RPW; ++i) sm[i] = 0.f;
      for (int jb = lane; jb < n; jb += 64) {
        const float g = G2l[jb];
#pragma unroll
        for (int i = 0; i < RPW; ++i) sm[i] += expf(lrelu(f1r[i] + g) - m[i]);
      }
#pragma unroll
      for (int s = 32; s; s >>= 1)
#pragma unroll
        for (int i = 0; i < RPW; ++i) sm[i] += __shfl_xor(sm[i], s);
      float inv[RPW];
#pragma unroll
      for (int i = 0; i < RPW; ++i) inv[i] = 1.f / sm[i];

      // phase C: chunked PV; probs live in VGPRs, broadcast via readlane
      float acc[RPW];
#pragma unroll
      for (int i = 0; i < RPW; ++i) acc[i] = 0.f;
      for (int jc = 0; jc < n; jc += KT) {
        const int L = (n - jc < KT) ? (n - jc) : KT;
        __syncthreads();  // previous chunk fully consumed by all waves
        // block-cooperative stage of gathered EW rows [jc, jc+L)
        for (int t = tid; t < L * 16; t += 256) {
          const int jj = t >> 4, c = (t & 15) << 2;
          const int v = Skb[jc + jj];
          *reinterpret_cast<float4*>(&EWg[jj][c]) =
              *reinterpret_cast<const float4*>(&EWh[(size_t)v * DHH + c]);
        }
        // normalized probs for this chunk, in registers (overlaps staging)
        float p0[RPW], p1[RPW];
        {
          const float g0 = G2l[jc + lane];
          const float g1 = G2l[jc + 64 + lane];
#pragma unroll
          for (int i = 0; i < RPW; ++i) {
            p0[i] = expf(lrelu(f1r[i] + g0) - m[i]) * inv[i];
            p1[i] = expf(lrelu(f1r[i] + g1) - m[i]) * inv[i];
          }
        }
        __syncthreads();  // EWg ready
        const int L0 = L < 64 ? L : 64;
#pragma unroll 4
        for (int jj = 0; jj < L0; ++jj) {
          const float v = EWg[jj][lane];
          const int sl = jj;
#pragma unroll
          for (int i = 0; i < RPW; ++i) acc[i] = fmaf(rdlane(p0[i], sl), v, acc[i]);
        }
#pragma unroll 4
        for (int jj = 64; jj < L; ++jj) {
          const float v = EWg[jj][lane];
          const int sl = jj - 64;
#pragma unroll
          for (int i = 0; i < RPW; ++i) acc[i] = fmaf(rdlane(p1[i], sl), v, acc[i]);
        }
      }
      // epilogue: elu + positive-only atomic max into lat
#pragma unroll
      for (int i = 0; i < RPW; ++i) {
        if (act[i]) {
          const float o = elu_(acc[i]);
          if (o > 0.f) atomicMax(latp, __float_as_int(o));
        }
      }
    }
  }

  // ---- arrival counter; last block runs the finale ----
  __threadfence();
  __syncthreads();
  if (tid == 0)
    s_last = (__hip_atomic_fetch_add(done, 1, __ATOMIC_ACQ_REL,
                                     __HIP_MEMORY_SCOPE_AGENT) == NBLK - 1);
  __syncthreads();
  if (!s_last) return;

  // finale: latent pooling + dense head (single block, loops b = 0..3)
  const float cw = cls_w[tid];
  const float v1 = ac1[tid], v2 = ac2[tid];
  for (int b = 0; b < BB; ++b) {
    const float l0 = __hip_atomic_load(&lat[(0 * BB + b) * 256 + tid],
                                       __ATOMIC_ACQUIRE, __HIP_MEMORY_SCOPE_AGENT);
    const float l1 = __hip_atomic_load(&lat[(1 * BB + b) * 256 + tid],
                                       __ATOMIC_ACQUIRE, __HIP_MEMORY_SCOPE_AGENT);
    float t0 = cw * v1, t1 = cw * v2, t2 = l0 * v2, t3 = l1 * v2;
#pragma unroll
    for (int s = 32; s; s >>= 1) {
      t0 += __shfl_xor(t0, s); t1 += __shfl_xor(t1, s);
      t2 += __shfl_xor(t2, s); t3 += __shfl_xor(t3, s);
    }
    if (lane == 0) { red[wave][0] = t0; red[wave][1] = t1; red[wave][2] = t2; red[wave][3] = t3; }
    __syncthreads();
    const float ca1 = red[0][0] + red[1][0] + red[2][0] + red[3][0];
    const float d0  = red[0][1] + red[1][1] + red[2][1] + red[3][1];
    const float d1  = red[0][2] + red[1][2] + red[2][2] + red[3][2];
    const float d2  = red[0][3] + red[1][3] + red[2][3] + red[3][3];
    const float e0 = lrelu(ca1 + d0), e1 = lrelu(ca1 + d1), e2 = lrelu(ca1 + d2);
    const float mm = fmaxf(e0, fmaxf(e1, e2));
    const float x0 = expf(e0 - mm), x1 = expf(e1 - mm), x2 = expf(e2 - mm);
    const float invs = 1.f / (x0 + x1 + x2);
    pooled[tid] = (x0 * cw + x1 * l0 + x2 * l1) * invs;
    __syncthreads();
    if (tid < PP) {
      float acc = db[tid];
      for (int f = 0; f < 256; ++f) acc = fmaf(pooled[f], dW[f * PP + tid], acc);
      out[b * PP + tid] = elu_(acc);
    }
    __syncthreads();  // pooled/red reused next iteration
  }
}

extern "C" void kernel_launch(void* const* d_in, const int* in_sizes, int n_in,
                              void* d_out, int out_size, void* d_ws, size_t ws_size,
                              hipStream_t stream) {
  const float* x     = (const float*)d_in[0];
  const float* E     = (const float*)d_in[1];
  const float* W     = (const float*)d_in[2];
  const float* a1    = (const float*)d_in[3];
  const float* a2    = (const float*)d_in[4];
  const float* cls_w = (const float*)d_in[5];
  const float* ac1   = (const float*)d_in[6];
  const float* ac2   = (const float*)d_in[7];
  const float* dW    = (const float*)d_in[8];
  const float* db    = (const float*)d_in[9];
  float* out = (float*)d_out;

  float* ws  = (float*)d_ws;
  float* EW  = ws + OFF_EW;
  float* F1  = ws + OFF_F1;
  float* F2  = ws + OFF_F2;
  float* LAT = ws + OFF_LAT;
  int*   CNT = (int*)(ws + OFF_CNT);
  int*   S   = (int*)(ws + OFF_S);
  int*   DONE = (int*)(ws + OFF_DONE);

  k_pre<<<2008, 256, 0, stream>>>(E, W, a1, a2, x, EW, F1, F2, S, CNT, LAT, DONE);
  k_attn<<<dim3(KK * BB, YB, HH), 256, 0, stream>>>(EW, F1, F2, S, CNT, LAT,
                                                    cls_w, ac1, ac2, dW, db, out, DONE);
}

// Round 5
// 31.679 us; speedup vs baseline: 2.6491x; 2.6491x over previous
//
#include <hip/hip_runtime.h>
#include <hip/hip_bf16.h>

// Problem constants (from reference)
#define KK 2
#define BB 4
#define VV 2000
#define DD 64
#define HH 4
#define DHH 64
#define PP 128
#define ALPHA_ 0.2f

// k_attn geometry
#define RPB 32                // rows per block-tile (2 MFMA row-tiles)
#define YB  8                 // y-blocks (tiles strided by YB)

typedef __attribute__((ext_vector_type(8))) short bf16x8;
typedef __attribute__((ext_vector_type(4))) float f32x4;

__device__ __forceinline__ float lrelu(float z) { return fmaxf(z, ALPHA_ * z); }
__device__ __forceinline__ float elu_(float z)  { return z > 0.f ? z : expm1f(z); }
__device__ __forceinline__ short f2bf(float f) {
  __hip_bfloat16 h = __float2bfloat16(f);
  return *reinterpret_cast<short*>(&h);
}

// ---------------------------------------------------------------------------
// Workspace layout (float offsets):
//   EW  [H][V][DH]   : 0        (512000)
//   F1  [H][V]       : 512000   (8000)
//   F2  [H][V]       : 520000   (8000)
//   LAT [K][B][256]  : 528000   (2048)
//   CNT (int)[8]     : 530048   (8)
//   S   (int)[K*B][V]: 530056   (16000)
// ---------------------------------------------------------------------------
#define OFF_EW   0
#define OFF_F1   512000
#define OFF_F2   520000
#define OFF_LAT  528000
#define OFF_CNT  530048
#define OFF_S    530056

// ---- kernel 0 (fused): EW/F1/F2 precompute (present rows only) + compaction
__global__ __launch_bounds__(256) void k_pre(
    const float* __restrict__ E, const float* __restrict__ W,
    const float* __restrict__ a1, const float* __restrict__ a2,
    const float* __restrict__ x,
    float* __restrict__ EW, float* __restrict__ F1, float* __restrict__ F2,
    int* __restrict__ S, int* __restrict__ cnt, float* __restrict__ lat) {
  const int bid = blockIdx.x;
  const int wave = threadIdx.x >> 6, lane = threadIdx.x & 63;
  if (bid < 2000) {
    const int h = bid / 500;                 // h-major: W_h stays L1-hot
    const int v = (bid % 500) * 4 + wave;
    bool pres = false;                       // skip rows absent in all slices
#pragma unroll
    for (int kb = 0; kb < KK * BB; ++kb) pres |= (x[kb * VV + v] > 0.f);
    if (!pres) return;
    const float* Wh = W + h * DD * DHH;
    const float* Ev = E + v * DD;
    float acc = 0.f;
#pragma unroll 8
    for (int d = 0; d < DD; ++d) acc = fmaf(Ev[d], Wh[d * DHH + lane], acc);
    EW[(h * VV + v) * DHH + lane] = acc;
    float r1 = acc * a1[h * DHH + lane];
    float r2 = acc * a2[h * DHH + lane];
#pragma unroll
    for (int s = 32; s; s >>= 1) { r1 += __shfl_xor(r1, s); r2 += __shfl_xor(r2, s); }
    if (lane == 0) { F1[h * VV + v] = r1; F2[h * VV + v] = r2; }
  } else {
    if (wave != 0) return;
    const int kb = bid - 2000;  // 0..7
    for (int i = lane; i < 256; i += 64) lat[kb * 256 + i] = 0.f;
    const float* xr = x + kb * VV;
    int base = 0;
    for (int t = 0; t * 64 < VV; ++t) {
      const int v = t * 64 + lane;
      const bool f = (v < VV) && (xr[v] > 0.f);
      const unsigned long long m = __ballot(f);
      if (f) {
        const int pos = base + __popcll(m & ((1ull << lane) - 1ull));
        S[kb * VV + pos] = v;
      }
      base += __popcll(m);
    }
    if (lane == 0) cnt[kb] = base;
  }
}

// ---- kernel 1: attention rows via MFMA ------------------------------------
// block = (kb, tile-stride y, h); 32 rows per tile. Softmax stats in f32
// (wave w owns rows 8w..8w+8), then PV as bf16 MFMA 16x16x32:
//   A = P (computed per-lane in registers, no LDS broadcast)
//   B = EW columns (direct L2 gathers), wave w owns cols 16w..16w+16.
__global__ __launch_bounds__(256) void k_attn(
    const float* __restrict__ EW, const float* __restrict__ F1,
    const float* __restrict__ F2, const int* __restrict__ S,
    const int* __restrict__ cnt, float* __restrict__ lat) {
  __shared__ int   Sl[2048];     // compacted indices (padded)
  __shared__ float G2l[2048];    // gathered F2 (padded with 0)
  __shared__ float G1l[2048];    // gathered F1
  __shared__ float SF1[RPB], SM[RPB], SIV[RPB];  // per-tile row stats

  const int kb = blockIdx.x;     // 0..7
  const int h  = blockIdx.z;     // 0..3
  const int tid = threadIdx.x;
  const int wave = tid >> 6, lane = tid & 63;
  const int n = cnt[kb];
  const int nt = (n + RPB - 1) / RPB;
  if ((int)blockIdx.y >= nt) return;
  const int nup = (n + 31) & ~31;

  const int* Skb = S + kb * VV;
  const float* F2h = F2 + h * VV;
  const float* F1h = F1 + h * VV;
  const float* EWh = EW + (size_t)h * VV * DHH;

  // stage indices + gathered F1/F2 once per block
  for (int j = tid; j < nup; j += 256) {
    const int v = (j < n) ? Skb[j] : Skb[0];
    Sl[j] = v;
    G2l[j] = (j < n) ? F2h[v] : 0.f;
    G1l[j] = F1h[v];
  }
  __syncthreads();

  const int col = (wave << 4) | (lane & 15);   // output/B column
  const int q   = lane >> 4;                   // K-quarter
  const float* EWcol = EWh + col;

  for (int tile = blockIdx.y; tile < nt; tile += YB) {
    // ---- softmax stats: wave owns rows r0w..r0w+8 ----
    const int r0w = tile * RPB + wave * 8;
    bool act[8]; float f1r[8];
#pragma unroll
    for (int i = 0; i < 8; ++i) {
      const int r = r0w + i;
      act[i] = r < n;
      f1r[i] = G1l[act[i] ? r : 0];
    }
    float m[8];
#pragma unroll
    for (int i = 0; i < 8; ++i) m[i] = -3.4e38f;
    for (int jb = lane; jb < n; jb += 64) {
      const float g = G2l[jb];
#pragma unroll
      for (int i = 0; i < 8; ++i) m[i] = fmaxf(m[i], lrelu(f1r[i] + g));
    }
#pragma unroll
    for (int s = 32; s; s >>= 1)
#pragma unroll
      for (int i = 0; i < 8; ++i) m[i] = fmaxf(m[i], __shfl_xor(m[i], s));
    float sm[8];
#pragma unroll
    for (int i = 0; i < 8; ++i) sm[i] = 0.f;
    for (int jb = lane; jb < n; jb += 64) {
      const float g = G2l[jb];
#pragma unroll
      for (int i = 0; i < 8; ++i) sm[i] += __expf(lrelu(f1r[i] + g) - m[i]);
    }
#pragma unroll
    for (int s = 32; s; s >>= 1)
#pragma unroll
      for (int i = 0; i < 8; ++i) sm[i] += __shfl_xor(sm[i], s);

    __syncthreads();  // previous tile's MFMA phase done reading stats
    if (lane == 0) {
#pragma unroll
      for (int i = 0; i < 8; ++i) {
        SF1[wave * 8 + i] = f1r[i];
        SM[wave * 8 + i]  = m[i];
        SIV[wave * 8 + i] = act[i] ? (1.f / sm[i]) : 0.f;
      }
    }
    __syncthreads();  // stats visible to all waves

    // ---- MFMA PV phase: wave w computes cols 16w..16w+16, rows 0..31 ----
    const int rl = lane & 15;
    const float f1a = SF1[rl],      ma = SM[rl],      ia = SIV[rl];
    const float f1b = SF1[16 + rl], mb = SM[16 + rl], ib = SIV[16 + rl];
    f32x4 acc0 = {0.f, 0.f, 0.f, 0.f}, acc1 = {0.f, 0.f, 0.f, 0.f};
    for (int kc = 0; kc < nup; kc += 32) {
      const int kq = kc + q * 8;
      const int4 va = *reinterpret_cast<const int4*>(&Sl[kq]);
      const int4 vb = *reinterpret_cast<const int4*>(&Sl[kq + 4]);
      const float4 ga = *reinterpret_cast<const float4*>(&G2l[kq]);
      const float4 gb = *reinterpret_cast<const float4*>(&G2l[kq + 4]);
      // B fragment: 8 gathered EW column values (L2-resident)
      float bv[8];
      bv[0] = EWcol[(size_t)va.x * DHH];
      bv[1] = EWcol[(size_t)va.y * DHH];
      bv[2] = EWcol[(size_t)va.z * DHH];
      bv[3] = EWcol[(size_t)va.w * DHH];
      bv[4] = EWcol[(size_t)vb.x * DHH];
      bv[5] = EWcol[(size_t)vb.y * DHH];
      bv[6] = EWcol[(size_t)vb.z * DHH];
      bv[7] = EWcol[(size_t)vb.w * DHH];
      const float g[8] = {ga.x, ga.y, ga.z, ga.w, gb.x, gb.y, gb.z, gb.w};
      // A fragments: probabilities for rows rl and 16+rl, K-slice kq..kq+8
      float pa[8], pb[8];
#pragma unroll
      for (int t = 0; t < 8; ++t) {
        const float gt = g[t];
        pa[t] = __expf(lrelu(f1a + gt) - ma) * ia;
        pb[t] = __expf(lrelu(f1b + gt) - mb) * ib;
      }
      if (kc + 32 > n) {  // K-tail: zero out-of-range columns
#pragma unroll
        for (int t = 0; t < 8; ++t)
          if (kq + t >= n) { pa[t] = 0.f; pb[t] = 0.f; }
      }
      bf16x8 A0, A1, Bf;
#pragma unroll
      for (int t = 0; t < 8; ++t) {
        A0[t] = f2bf(pa[t]);
        A1[t] = f2bf(pb[t]);
        Bf[t] = f2bf(bv[t]);
      }
      acc0 = __builtin_amdgcn_mfma_f32_16x16x32_bf16(A0, Bf, acc0, 0, 0, 0);
      acc1 = __builtin_amdgcn_mfma_f32_16x16x32_bf16(A1, Bf, acc1, 0, 0, 0);
    }
    // ---- epilogue: lat[col] = max(0, max_rows elu(out)) ----
    // elu(v)=v for v>0 and non-positives never beat the 0-init -> just max.
    float vmax = -3.4e38f;
#pragma unroll
    for (int r = 0; r < 4; ++r) {
      const int row0 = tile * RPB + (q << 2) + r;        // D row, tile rt=0
      const int row1 = row0 + 16;                        // tile rt=1
      if (row0 < n) vmax = fmaxf(vmax, acc0[r]);
      if (row1 < n) vmax = fmaxf(vmax, acc1[r]);
    }
    if (vmax > 0.f)
      atomicMax(reinterpret_cast<int*>(&lat[kb * 256 + h * DHH + col]),
                __float_as_int(vmax));
  }
}

// ---- kernel 2: latent pooling + dense head; one block per batch -----------
__global__ __launch_bounds__(256) void k_final(
    const float* __restrict__ cls_w, const float* __restrict__ ac1,
    const float* __restrict__ ac2, const float* __restrict__ dW,
    const float* __restrict__ db, const float* __restrict__ lat,
    float* __restrict__ out) {
  const int b = blockIdx.x;
  const int tid = threadIdx.x;  // 256
  const int lane = tid & 63, wave = tid >> 6;
  __shared__ float pooled[256];
  __shared__ float red[4][4];
  const float cw = cls_w[tid];
  const float l0 = lat[(0 * BB + b) * 256 + tid];
  const float l1 = lat[(1 * BB + b) * 256 + tid];
  float t0 = cw * ac1[tid];
  float t1 = cw * ac2[tid];
  float t2 = l0 * ac2[tid];
  float t3 = l1 * ac2[tid];
#pragma unroll
  for (int s = 32; s; s >>= 1) {
    t0 += __shfl_xor(t0, s); t1 += __shfl_xor(t1, s);
    t2 += __shfl_xor(t2, s); t3 += __shfl_xor(t3, s);
  }
  if (lane == 0) { red[wave][0] = t0; red[wave][1] = t1; red[wave][2] = t2; red[wave][3] = t3; }
  __syncthreads();
  const float ca1 = red[0][0] + red[1][0] + red[2][0] + red[3][0];
  const float d0  = red[0][1] + red[1][1] + red[2][1] + red[3][1];
  const float d1  = red[0][2] + red[1][2] + red[2][2] + red[3][2];
  const float d2  = red[0][3] + red[1][3] + red[2][3] + red[3][3];
  const float e0 = lrelu(ca1 + d0), e1 = lrelu(ca1 + d1), e2 = lrelu(ca1 + d2);
  const float mm = fmaxf(e0, fmaxf(e1, e2));
  const float x0 = __expf(e0 - mm), x1 = __expf(e1 - mm), x2 = __expf(e2 - mm);
  const float invs = 1.f / (x0 + x1 + x2);
  pooled[tid] = (x0 * cw + x1 * l0 + x2 * l1) * invs;
  __syncthreads();
  if (tid < PP) {
    float acc = db[tid];
    for (int f = 0; f < 256; ++f) acc = fmaf(pooled[f], dW[f * PP + tid], acc);
    out[b * PP + tid] = elu_(acc);
  }
}

extern "C" void kernel_launch(void* const* d_in, const int* in_sizes, int n_in,
                              void* d_out, int out_size, void* d_ws, size_t ws_size,
                              hipStream_t stream) {
  const float* x     = (const float*)d_in[0];
  const float* E     = (const float*)d_in[1];
  const float* W     = (const float*)d_in[2];
  const float* a1    = (const float*)d_in[3];
  const float* a2    = (const float*)d_in[4];
  const float* cls_w = (const float*)d_in[5];
  const float* ac1   = (const float*)d_in[6];
  const float* ac2   = (const float*)d_in[7];
  const float* dW    = (const float*)d_in[8];
  const float* db    = (const float*)d_in[9];
  float* out = (float*)d_out;

  float* ws  = (float*)d_ws;
  float* EW  = ws + OFF_EW;
  float* F1  = ws + OFF_F1;
  float* F2  = ws + OFF_F2;
  float* LAT = ws + OFF_LAT;
  int*   CNT = (int*)(ws + OFF_CNT);
  int*   S   = (int*)(ws + OFF_S);

  k_pre<<<2008, 256, 0, stream>>>(E, W, a1, a2, x, EW, F1, F2, S, CNT, LAT);
  k_attn<<<dim3(KK * BB, YB, HH), 256, 0, stream>>>(EW, F1, F2, S, CNT, LAT);
  k_final<<<BB, 256, 0, stream>>>(cls_w, ac1, ac2, dW, db, LAT, out);
}